// Round 4
// baseline (1091.859 us; speedup 1.0000x reference)
//
#include <hip/hip_runtime.h>
#include <stdint.h>

typedef unsigned short u16;
using frag8 = __attribute__((ext_vector_type(8))) short;
using f32x4 = __attribute__((ext_vector_type(4))) float;

#define NTOK 32768
#define FDIM 512

__device__ __forceinline__ float bflo(uint32_t p){ union{uint32_t u; float f;} v; v.u = p<<16; return v.f; }
__device__ __forceinline__ float bfhi(uint32_t p){ union{uint32_t u; float f;} v; v.u = p & 0xffff0000u; return v.f; }
__device__ __forceinline__ float bf1(u16 x){ union{uint32_t u; float f;} v; v.u = ((uint32_t)x)<<16; return v.f; }
__device__ __forceinline__ u16 f2bf(float f){
  union{float f; uint32_t u;} v; v.f = f;
  uint32_t u = v.u;
  u += 0x7fffu + ((u>>16)&1u);   // round-to-nearest-even
  return (u16)(u>>16);
}

__device__ __forceinline__ void async16(const void* g, void* l){
  __builtin_amdgcn_global_load_lds((const __attribute__((address_space(1))) uint32_t*)g,
                                   (__attribute__((address_space(3))) uint32_t*)l, 16, 0, 0);
}

// -------------------- embedding + positional encoding (bf16 x only) --------------------
__global__ __launch_bounds__(256) void embed_kernel(const int* __restrict__ text,
    const float* __restrict__ emb, const float* __restrict__ pe,
    u16* __restrict__ xb, const int tok0){
  const int gid = blockIdx.x*256 + threadIdx.x;
  const int base = gid*4;
  const int tl = base >> 9;
  const int f  = base & 511;
  const int tg = tl + tok0;
  const int s  = tg & 511;
  const int tok = text[tg];
  const float4 e4 = *(const float4*)(emb + (size_t)tok*FDIM + f);
  const float4 p4 = *(const float4*)(pe  + (size_t)s*FDIM + f);
  ushort4 ob;
  ob.x = f2bf(e4.x + p4.x);
  ob.y = f2bf(e4.y + p4.y);
  ob.z = f2bf(e4.z + p4.z);
  ob.w = f2bf(e4.w + p4.w);
  *(ushort4*)(xb + base) = ob;
}

// -------------------- weight transpose + fp32->bf16: WT[lay][n][k], n: Wq|Wk|Wv|Wf --------------------
__global__ __launch_bounds__(256) void transpose_w(const float* __restrict__ Wq,
    const float* __restrict__ Wk, const float* __restrict__ Wv, const float* __restrict__ Wf,
    u16* __restrict__ WT){
  const int gid = blockIdx.x*256 + threadIdx.x;
  const int n   = gid & 2047;
  const int k8  = (gid>>11) & 63;
  const int lay = gid >> 17;
  const float* src; int col;
  if      (n <  512){ src = Wq; col = n;      }
  else if (n < 1024){ src = Wk; col = n-512;  }
  else if (n < 1536){ src = Wv; col = n-1024; }
  else              { src = Wf; col = n-1536; }
  src += (size_t)lay*FDIM*FDIM;
  u16 vals[8] __attribute__((aligned(16)));
  #pragma unroll
  for (int i=0;i<8;i++) vals[i] = f2bf(src[(size_t)(k8*8+i)*FDIM + col]);
  *(int4*)(WT + ((size_t)lay*2048 + n)*FDIM + k8*8) = *(const int4*)vals;
}

// -------------------- 256x256 ring-4 pipelined MFMA GEMM (R1 structure, best measured) ----------
template<int MODE>
__global__ __launch_bounds__(512, 2) void gemm256(
    const u16* __restrict__ A, const u16* __restrict__ BT,
    const float* __restrict__ b0, const float* __restrict__ b1, const float* __restrict__ b2,
    const u16* __restrict__ resid, u16* __restrict__ C, const int ldC, const int NB){
  __shared__ __attribute__((aligned(16))) short As[4*256*32];   // 64 KiB
  __shared__ __attribute__((aligned(16))) short Bs[4*256*32];   // 64 KiB
  const int nwg = gridDim.x;
  const int orig = blockIdx.x;
  const int wg = ((nwg & 7) == 0) ? ((orig & 7)*(nwg >> 3) + (orig >> 3)) : orig;
  const int nblk = wg % NB, mblk = wg / NB;
  const int m0 = mblk << 8, n0 = nblk << 8;
  const int tid = threadIdx.x;
  const int wid = tid >> 6, l = tid & 63;
  const int lm = l & 15, quad = l >> 4;

  const int srow = wid*16 + (l >> 2);
  const int sch  = (l & 3) ^ ((l >> 3) & 3);
  const char* Asrc0 = (const char*)A  + ((size_t)(m0 + srow))*1024 + sch*16;
  const char* Asrc1 = Asrc0 + 128*1024;
  const char* Bsrc0 = (const char*)BT + ((size_t)(n0 + srow))*1024 + sch*16;
  const char* Bsrc1 = Bsrc0 + 128*1024;
  char* ldsAw = (char*)As + wid*1024;
  char* ldsBw = (char*)Bs + wid*1024;

  f32x4 acc[8][4];
  #pragma unroll
  for (int i=0;i<8;i++)
    #pragma unroll
    for (int j=0;j<4;j++){ f32x4 z = {0.f,0.f,0.f,0.f}; acc[i][j] = z; }

  const int rsel = quad ^ ((lm >> 1) & 3);
  const int aB = ((wid>>2)*128 + lm)*32 + rsel*8;
  const int bB = ((wid&3)*64  + lm)*32 + rsel*8;

  #pragma unroll
  for (int kt=0; kt<3; kt++){
    async16(Asrc0 + kt*64, ldsAw + kt*16384);
    async16(Asrc1 + kt*64, ldsAw + kt*16384 + 8192);
    async16(Bsrc0 + kt*64, ldsBw + kt*16384);
    async16(Bsrc1 + kt*64, ldsBw + kt*16384 + 8192);
  }

  for (int t=0; t<16; ++t){
    if (t < 14)       asm volatile("s_waitcnt vmcnt(8)" ::: "memory");
    else if (t == 14) asm volatile("s_waitcnt vmcnt(4)" ::: "memory");
    else              asm volatile("s_waitcnt vmcnt(0)" ::: "memory");
    __builtin_amdgcn_s_barrier();
    asm volatile("" ::: "memory");
    const int slot = t & 3;
    const short* sA = As + slot*8192;
    const short* sB = Bs + slot*8192;
    frag8 af[4], bfrg[4], ag[4];
    #pragma unroll
    for (int mi=0; mi<4; mi++) af[mi] = *(const frag8*)(sA + aB + mi*512);
    #pragma unroll
    for (int nj=0; nj<4; nj++) bfrg[nj] = *(const frag8*)(sB + bB + nj*512);
    if (t < 13){
      const int s3 = (t+3) & 3, off = (t+3)*64;
      async16(Asrc0 + off, ldsAw + s3*16384);
      async16(Asrc1 + off, ldsAw + s3*16384 + 8192);
    }
    __builtin_amdgcn_s_setprio(1);
    #pragma unroll
    for (int mi=0; mi<4; mi++)
      #pragma unroll
      for (int nj=0; nj<4; nj++)
        acc[mi][nj] = __builtin_amdgcn_mfma_f32_16x16x32_bf16(af[mi], bfrg[nj], acc[mi][nj], 0,0,0);
    __builtin_amdgcn_s_setprio(0);
    #pragma unroll
    for (int mi=0; mi<4; mi++) ag[mi] = *(const frag8*)(sA + aB + 2048 + mi*512);
    if (t < 13){
      const int s3 = (t+3) & 3, off = (t+3)*64;
      async16(Bsrc0 + off, ldsBw + s3*16384);
      async16(Bsrc1 + off, ldsBw + s3*16384 + 8192);
    }
    __builtin_amdgcn_s_setprio(1);
    #pragma unroll
    for (int mi=0; mi<4; mi++)
      #pragma unroll
      for (int nj=0; nj<4; nj++)
        acc[4+mi][nj] = __builtin_amdgcn_mfma_f32_16x16x32_bf16(ag[mi], bfrg[nj], acc[4+mi][nj], 0,0,0);
    __builtin_amdgcn_s_setprio(0);
  }

  float bias[4]; int cols[4];
  #pragma unroll
  for (int nj=0;nj<4;nj++){
    const int c = n0 + (wid&3)*64 + nj*16 + lm;
    cols[nj] = c;
    if (MODE==0) bias[nj] = (c<512 ? b0[c] : (c<1024 ? b1[c-512] : b2[c-1024]));
    else         bias[nj] = b0[c];
  }
  #pragma unroll
  for (int mi=0; mi<8; mi++){
    const int rbase = m0 + (wid>>2)*128 + mi*16 + quad*4;
    #pragma unroll
    for (int r=0;r<4;r++){
      const size_t row = (size_t)(rbase + r);
      #pragma unroll
      for (int nj=0;nj<4;nj++){
        float v = acc[mi][nj][r] + bias[nj];
        if (MODE==1) v += bf1(resid[row*FDIM + cols[nj]]);
        C[row*(size_t)ldC + cols[nj]] = f2bf(v);
      }
    }
  }
}

// -------------------- FUSED: attention + residual + LN1 + FF-GEMM(+resid) + LN2 --------------------
// Block = 64 tokens, 512 threads (8 waves). LDS: y1S 64KB (LN1 output, XOR-swizzled, serves as the
// FF-GEMM A operand) + Bs 64KB (Wf ring-2; slot1 doubles as per-wave attention scratch in phase 1).
// Phase 1: wave w handles tokens w*8..w*8+7 with the per-token head-attention routine, writes y1
//   rows to y1S at chunk l^f(tl), f(row)=((row>>1)&3)|(((row>>3)&1)<<2)  [2-way banks on all paths].
// Phase 2: FF gemm, A resident in y1S (frag chunk (4t+quad)^f(lm)), B double-buffered via
//   global_load_lds from WT-Wf section (L2-hot). z-residual read back from y1S (exact).
// Epilogue: LN2 on unrounded f32 z; cross-wave row stats via 2KB LDS; in-place xb update / f32 out.
__global__ __launch_bounds__(512, 2) void attn_ff_fused(
    const u16* __restrict__ qkvb, u16* __restrict__ xb,
    const u16* __restrict__ WTf,
    const float* __restrict__ g1, const float* __restrict__ be1,
    const float* __restrict__ bfv,
    const float* __restrict__ g2, const float* __restrict__ be2,
    float* __restrict__ outp, const int final_){
  __shared__ __attribute__((aligned(16))) short y1S[64*512];   // 64 KiB
  __shared__ __attribute__((aligned(16))) short Bs[2*512*32];  // 64 KiB
  const int m0 = blockIdx.x * 64;
  const int tid = threadIdx.x;
  const int wid = tid>>6, l = tid&63;
  const int lm = l&15, quad = l>>4;
  const int wm = wid>>2, wn = wid&3;

  // ---- B staging: per-lane pre-swizzled global source, linear LDS dest ----
  const int sch = (l&3) ^ ((l>>3)&3);
  const u16* bsrc = WTf + (size_t)(wid*16 + (l>>2))*512 + sch*8;
  char* ldsBw = (char*)Bs + wid*1024;

#define STAGEB(TT_, S_) { \
    _Pragma("unroll") \
    for (int r_=0;r_<4;r_++) \
      async16(bsrc + (TT_)*32 + r_*65536, ldsBw + (S_)*32768 + r_*8192); }

  STAGEB(0, 0)   // prefetch FF K-tile 0 under phase 1

  // ---------------- phase 1: attention + residual + LN1 -> y1S ----------------
  {
    char* scr = (char*)Bs + 32768 + wid*4096;   // slot1 region; 8 waves x 4KB
    u16* sq = (u16*)scr;
    float* swt = (float*)(scr + 3072);
    const float4 ga0 = *(const float4*)(g1 + l*8);
    const float4 ga1 = *(const float4*)(g1 + l*8 + 4);
    const float4 bb0 = *(const float4*)(be1 + l*8);
    const float4 bb1 = *(const float4*)(be1 + l*8 + 4);
    for (int tk=0; tk<8; tk++){
      const int t = m0 + wid*8 + tk;
      {
        const int4* src = (const int4*)(qkvb + (size_t)t*1536);
        int4* dst = (int4*)sq;
        #pragma unroll
        for (int i=0;i<3;i++) dst[i*64 + l] = src[i*64 + l];
      }
      const int h = l>>3, g = l&7;
      const u16* qrow = sq + h*64;
      const u16* krow = sq + 512 + g*64;
      float sc = 0.f;
      const int dstart = (l&31)*2;
      #pragma unroll
      for (int i=0;i<32;i++){
        const int d = (dstart + 2*i) & 63;
        const uint32_t qp = *(const uint32_t*)(qrow + d);
        const uint32_t kp = *(const uint32_t*)(krow + d);
        sc += bflo(qp)*bflo(kp) + bfhi(qp)*bfhi(kp);
      }
      float mx = sc;
      mx = fmaxf(mx, __shfl_xor(mx,1));
      mx = fmaxf(mx, __shfl_xor(mx,2));
      mx = fmaxf(mx, __shfl_xor(mx,4));
      const float e = __expf(sc - mx);
      float ssum = e;
      ssum += __shfl_xor(ssum,1);
      ssum += __shfl_xor(ssum,2);
      ssum += __shfl_xor(ssum,4);
      swt[l] = e / ssum;
      float wt[8];
      #pragma unroll
      for (int gg=0;gg<8;gg++) wt[gg] = swt[h*8+gg];
      float att[8] = {0,0,0,0,0,0,0,0};
      const int d0 = (l&7)*8;
      #pragma unroll
      for (int gg=0;gg<8;gg++){
        const int4 vv = *(const int4*)(sq + 1024 + gg*64 + d0);
        const uint32_t* vp = (const uint32_t*)&vv;
        #pragma unroll
        for (int p=0;p<4;p++){
          att[2*p]   += wt[gg]*bflo(vp[p]);
          att[2*p+1] += wt[gg]*bfhi(vp[p]);
        }
      }
      const size_t rb = (size_t)t*FDIM + l*8;
      const int4 xv = *(const int4*)(xb + rb);
      const uint32_t* xp = (const uint32_t*)&xv;
      float y[8]; float s1=0.f, s2=0.f;
      #pragma unroll
      for (int p=0;p<4;p++){
        y[2*p]   = att[2*p]   + bflo(xp[p]);
        y[2*p+1] = att[2*p+1] + bfhi(xp[p]);
      }
      #pragma unroll
      for (int j=0;j<8;j++){ s1 += y[j]; s2 += y[j]*y[j]; }
      #pragma unroll
      for (int off=1; off<64; off<<=1){ s1 += __shfl_xor(s1,off); s2 += __shfl_xor(s2,off); }
      const float mean = s1*(1.f/512.f);
      const float var  = s2*(1.f/512.f) - mean*mean;
      const float rstd = rsqrtf(var + 1e-5f);
      float of[8];
      of[0]=(y[0]-mean)*rstd*ga0.x + bb0.x;
      of[1]=(y[1]-mean)*rstd*ga0.y + bb0.y;
      of[2]=(y[2]-mean)*rstd*ga0.z + bb0.z;
      of[3]=(y[3]-mean)*rstd*ga0.w + bb0.w;
      of[4]=(y[4]-mean)*rstd*ga1.x + bb1.x;
      of[5]=(y[5]-mean)*rstd*ga1.y + bb1.y;
      of[6]=(y[6]-mean)*rstd*ga1.z + bb1.z;
      of[7]=(y[7]-mean)*rstd*ga1.w + bb1.w;
      u16 ob[8] __attribute__((aligned(16)));
      #pragma unroll
      for (int j=0;j<8;j++) ob[j] = f2bf(of[j]);
      const int tl = wid*8 + tk;
      const int fx = ((tl>>1)&3) | (((tl>>3)&1)<<2);
      *(int4*)((char*)y1S + tl*1024 + ((l ^ fx)<<4)) = *(const int4*)ob;
    }
  }
  __syncthreads();   // y1S complete; scratch (slot1) dead; prologue stage drained

  // ---------------- phase 2: FF gemm, A from y1S, B ring-2 ----------------
  f32x4 acc[2][8];
  #pragma unroll
  for (int i=0;i<2;i++)
    #pragma unroll
    for (int j=0;j<8;j++){ f32x4 z = {0.f,0.f,0.f,0.f}; acc[i][j] = z; }
  const int axor = ((lm>>1)&3) | (((lm>>3)&1)<<2);
  const int aBase = (wm*32 + lm)*512;
  const int bOff = (wn*128 + lm)*32 + (quad ^ ((lm>>1)&3))*8;

#define FTILE2(T_, DOSTAGE) { \
    asm volatile("s_waitcnt vmcnt(0)" ::: "memory"); \
    __builtin_amdgcn_s_barrier(); \
    asm volatile("" ::: "memory"); \
    if (DOSTAGE){ STAGEB((T_)+1, ((T_)+1)&1) } \
    const short* sB_ = Bs + ((T_)&1)*16384; \
    frag8 af_[2], bf_[8]; \
    _Pragma("unroll") \
    for (int mi_=0;mi_<2;mi_++) \
      af_[mi_] = *(const frag8*)(y1S + aBase + mi_*8192 + (((((T_)*4)+quad)^axor)<<3)); \
    _Pragma("unroll") \
    for (int nj_=0;nj_<8;nj_++) bf_[nj_] = *(const frag8*)(sB_ + bOff + nj_*512); \
    __builtin_amdgcn_s_setprio(1); \
    _Pragma("unroll") \
    for (int mi_=0;mi_<2;mi_++) \
      _Pragma("unroll") \
      for (int nj_=0;nj_<8;nj_++) \
        acc[mi_][nj_] = __builtin_amdgcn_mfma_f32_16x16x32_bf16(af_[mi_], bf_[nj_], acc[mi_][nj_], 0,0,0); \
    __builtin_amdgcn_s_setprio(0); }

  FTILE2(0,1)  FTILE2(1,1)  FTILE2(2,1)  FTILE2(3,1)
  FTILE2(4,1)  FTILE2(5,1)  FTILE2(6,1)  FTILE2(7,1)
  FTILE2(8,1)  FTILE2(9,1)  FTILE2(10,1) FTILE2(11,1)
  FTILE2(12,1) FTILE2(13,1) FTILE2(14,1) FTILE2(15,0)
#undef FTILE2
#undef STAGEB

  // ---------------- epilogue: bias + y1 residual + LN2 + write ----------------
  __syncthreads();                       // all B reads done -> Bs reusable
  float* ln2S = (float*)Bs;              // [64 rows][4 wn][2] f32 = 2 KB
  int cols[8]; float bia[8], gg2[8], be2v[8];
  #pragma unroll
  for (int nj=0;nj<8;nj++){
    const int c = wn*128 + nj*16 + lm;
    cols[nj] = c; bia[nj] = bfv[c]; gg2[nj] = g2[c]; be2v[nj] = be2[c];
  }
  #pragma unroll
  for (int mi=0;mi<2;mi++){
    #pragma unroll
    for (int r=0;r<4;r++){
      const int row_l = wm*32 + mi*16 + quad*4 + r;
      const int frow = ((row_l>>1)&3) | (((row_l>>3)&1)<<2);
      #pragma unroll
      for (int nj=0;nj<8;nj++){
        const int c = cols[nj];
        const float resid = bf1(y1S[row_l*512 + (((c>>3)^frow)<<3) + (c&7)]);
        acc[mi][nj][r] += bia[nj] + resid;
      }
    }
  }
  #pragma unroll
  for (int mi=0;mi<2;mi++){
    #pragma unroll
    for (int r=0;r<4;r++){
      const int row_l = wm*32 + mi*16 + quad*4 + r;
      float s1 = 0.f, s2 = 0.f;
      #pragma unroll
      for (int nj=0;nj<8;nj++){ const float v = acc[mi][nj][r]; s1 += v; s2 += v*v; }
      s1 += __shfl_xor(s1,1); s2 += __shfl_xor(s2,1);
      s1 += __shfl_xor(s1,2); s2 += __shfl_xor(s2,2);
      s1 += __shfl_xor(s1,4); s2 += __shfl_xor(s2,4);
      s1 += __shfl_xor(s1,8); s2 += __shfl_xor(s2,8);
      if (lm == 0){
        ln2S[row_l*8 + wn*2]     = s1;
        ln2S[row_l*8 + wn*2 + 1] = s2;
      }
    }
  }
  __syncthreads();
  #pragma unroll
  for (int mi=0;mi<2;mi++){
    #pragma unroll
    for (int r=0;r<4;r++){
      const int row_l = wm*32 + mi*16 + quad*4 + r;
      const float s1t = ln2S[row_l*8] + ln2S[row_l*8+2] + ln2S[row_l*8+4] + ln2S[row_l*8+6];
      const float s2t = ln2S[row_l*8+1] + ln2S[row_l*8+3] + ln2S[row_l*8+5] + ln2S[row_l*8+7];
      const float mean = s1t*(1.f/512.f);
      const float var  = s2t*(1.f/512.f) - mean*mean;
      const float rstd = rsqrtf(var + 1e-5f);
      const size_t rg = (size_t)(m0 + row_l)*FDIM;
      if (final_){
        #pragma unroll
        for (int nj=0;nj<8;nj++){
          const float of = (acc[mi][nj][r]-mean)*rstd*gg2[nj] + be2v[nj];
          outp[rg + cols[nj]] = of;
        }
      } else {
        #pragma unroll
        for (int nj=0;nj<8;nj++){
          const float of = (acc[mi][nj][r]-mean)*rstd*gg2[nj] + be2v[nj];
          xb[rg + cols[nj]] = f2bf(of);
        }
      }
    }
  }
}

extern "C" void kernel_launch(void* const* d_in, const int* in_sizes, int n_in,
                              void* d_out, int out_size, void* d_ws, size_t ws_size,
                              hipStream_t stream){
  const int*   text = (const int*)d_in[0];
  const float* emb = (const float*)d_in[1];
  const float* pe  = (const float*)d_in[2];
  const float* Wq  = (const float*)d_in[3];
  const float* bq  = (const float*)d_in[4];
  const float* Wk  = (const float*)d_in[5];
  const float* bk  = (const float*)d_in[6];
  const float* Wv  = (const float*)d_in[7];
  const float* bv  = (const float*)d_in[8];
  const float* g1  = (const float*)d_in[9];
  const float* be1 = (const float*)d_in[10];
  const float* Wf  = (const float*)d_in[11];
  const float* bf_ = (const float*)d_in[12];
  const float* g2  = (const float*)d_in[13];
  const float* be2 = (const float*)d_in[14];
  float* outp = (float*)d_out;               // reference output dtype = float32

  // ---- layout: WT 12.6 MB + per-token {xb 1024 + qkv 3072} = 4096 B
  const size_t wtB = (size_t)6*2048*512*2;
  int T = NTOK;
  while (T > 2048 && wtB + (size_t)T*4096 > ws_size) T >>= 1;

  char* ws = (char*)d_ws;
  u16*   WT  = (u16*)ws;
  char*  act = ws + wtB;
  u16*   xb  = (u16*)act;                       // T*1024 B (updated in place per layer)
  u16*   qkv = (u16*)(act + (size_t)T*1024);    // T*3072 B

  hipLaunchKernelGGL(transpose_w, dim3(3072), dim3(256), 0, stream, Wq, Wk, Wv, Wf, WT);

  const int chunks = NTOK / T;
  for (int c = 0; c < chunks; c++){
    const int tok0 = c*T;
    hipLaunchKernelGGL(embed_kernel, dim3(T/2), dim3(256), 0, stream, text, emb, pe, xb, tok0);
    for (int lay=0; lay<6; lay++){
      const u16* WTl = WT + (size_t)lay*2048*FDIM;
      hipLaunchKernelGGL((gemm256<0>), dim3((T/256)*6), dim3(512), 0, stream,
          xb, WTl, bq + lay*FDIM, bk + lay*FDIM, bv + lay*FDIM, (const u16*)nullptr, qkv, 1536, 6);
      hipLaunchKernelGGL(attn_ff_fused, dim3(T/64), dim3(512), 0, stream,
          qkv, xb, WTl + (size_t)1536*FDIM,
          g1 + lay*FDIM, be1 + lay*FDIM, bf_ + lay*FDIM,
          g2 + lay*FDIM, be2 + lay*FDIM,
          outp + (size_t)tok0*FDIM, (lay==5)?1:0);
    }
  }
}